// Round 8
// baseline (649.127 us; speedup 1.0000x reference)
//
#include <hip/hip_runtime.h>
#include <cstdint>
#include <cstddef>

// ---------------------------------------------------------------------------
// Mamba3Block on MI355X. B=2, L=4096, D_MODEL=1024, D_INNER=D_STATE=2048.
// R14: k_g36 K-loop restructured as 4 phases/K-tile (T3+T4): each phase =
// {10-12 ds_read + 2 global_load_lds -> barrier -> lgkm0+schedbar ->
// setprio+16 MFMA -> [vmcnt(2)] barrier}. Wave-skew overlaps LDS reads with
// MFMA (R12/13 alternated them: ~4790 cyc/tile = reads+MFMA serialized).
// Periodic counted vmcnt(2) at ph1/ph4 ends; derivation: ph4-end vmcnt(2)
// guarantees next tile's A(full)+B1 landed (ph1 safe); ph1-end vmcnt(2)
// guarantees B2 (ph2-4 safe); tail tile uses vmcnt(0). Stage buffer is
// always the non-read buffer. Accumulation order unchanged (bitwise-same C).
// Also: cumsum_p1 fused into g36 epilogue (chunk col-sums from acc regs via
// shfl-reduce; BXC blocks own whole 64-row chunks). 7 dispatches.
// Kept: chunked-n XCD map for 128x128 cores, merged [WCBp;WXp], cumsum-
// commute algebra, fast softplus + NA precompute, cs23+scan1 fusion.
// ---------------------------------------------------------------------------

typedef unsigned short u16;                 // bf16 storage (bit pattern)
typedef __bf16 bf16x8 __attribute__((ext_vector_type(8)));
typedef float  f32x4  __attribute__((ext_vector_type(4)));

#define BDIM 256
#define M_ROWS 8192            // B*L
#define LSEQ   4096
#define DI     2048            // d_inner / d_state
#define NCH    64              // scan chunks
#define CLEN   64              // LSEQ / NCH

__device__ __forceinline__ float bf2f(u16 h) {
    return __uint_as_float(((unsigned int)h) << 16);
}
__device__ __forceinline__ u16 f2bf(float f) {
    unsigned int u = __float_as_uint(f);
    u = u + 0x7fffu + ((u >> 16) & 1u);     // RNE
    return (u16)(u >> 16);
}
__device__ __forceinline__ float siluf(float v) { return v / (1.0f + __expf(-v)); }

__device__ __forceinline__ void load16_to_lds(const u16* g, u16* l) {
    __builtin_amdgcn_global_load_lds((const __attribute__((address_space(1))) void*)g,
                                     (__attribute__((address_space(3))) void*)l,
                                     16, 0, 0);
}

// ---------------------------------------------------------------------------
// fused f32 -> bf16 convert of ALL inputs (1 launch), incl. +I diag segments,
// plus tail segment: NA[d] = -exp(A_log[d]) (f32, 2048 elems).
// ---------------------------------------------------------------------------
__global__ void k_cvt_all(const float* __restrict__ hs, const float* __restrict__ inproj,
                          const float* __restrict__ Bw, const float* __restrict__ Cw,
                          const float* __restrict__ outw, const float* __restrict__ delta,
                          const float* __restrict__ dtw, const float* __restrict__ Areal,
                          const float* __restrict__ Dw, const float* __restrict__ Alog,
                          u16* __restrict__ XH, u16* __restrict__ W1, u16* __restrict__ WBb,
                          u16* __restrict__ WC, u16* __restrict__ WO, u16* __restrict__ DLT,
                          u16* __restrict__ WDT, u16* __restrict__ Pb, u16* __restrict__ Db,
                          float* __restrict__ NA) {
    long i = (long)(blockIdx.x * BDIM + threadIdx.x) * 4;
    if (i >= 32112640L) {                       // NA tail: 2048 f32
        long j = i - 32112640L;
        if (j < 2048) {
            float4 v = *reinterpret_cast<const float4*>(Alog + j);
            float4 o = {-__expf(v.x), -__expf(v.y), -__expf(v.z), -__expf(v.w)};
            *reinterpret_cast<float4*>(NA + j) = o;
        }
        return;
    }
    const float* src; u16* dst; long off; bool diag = false;
    if      (i <  8388608L) { src = hs;     dst = XH;  off = 0L; }
    else if (i < 12582912L) { src = inproj; dst = W1;  off = 8388608L; }
    else if (i < 16777216L) { src = Bw;     dst = WBb; off = 12582912L; }
    else if (i < 20971520L) { src = Cw;     dst = WC;  off = 16777216L; }
    else if (i < 23068672L) { src = outw;   dst = WO;  off = 20971520L; }
    else if (i < 23592960L) { src = delta;  dst = DLT; off = 23068672L; }
    else if (i < 23724032L) { src = dtw;    dst = WDT; off = 23592960L; }
    else if (i < 27918336L) { src = Areal;  dst = Pb;  off = 23724032L; diag = true; }
    else                    { src = Dw;     dst = Db;  off = 27918336L; diag = true; }
    long j = i - off;
    float4 v = *reinterpret_cast<const float4*>(src + j);
    if (diag) {
        int r = (int)(j >> 11), c = (int)(j & 2047);
        if (r >= c && r < c + 4) (&v.x)[r - c] += 1.0f;
    }
    ushort2 a = {f2bf(v.x), f2bf(v.y)};
    ushort2 b = {f2bf(v.z), f2bf(v.w)};
    *reinterpret_cast<ushort2*>(dst + j)     = a;
    *reinterpret_cast<ushort2*>(dst + j + 2) = b;
}

// ---------------------------------------------------------------------------
// 128x128 GEMM tile core (proven): C_tile = A1*W1^T (+ A2*W2^T).
// LDS XOR-swizzle (r,c) -> r*64 + (c ^ ((r&7)*8)); staging = global_load_lds.
// mode 0: store bf16; 2: store f32; 5: log-decay bf16; 6: split; 8: transposed
// ---------------------------------------------------------------------------
__device__ __forceinline__ void gemm_core(
    u16* As, u16* Bs,
    const u16* __restrict__ A1, const u16* __restrict__ W1, int K1,
    const u16* __restrict__ A2, const u16* __restrict__ W2, int K2,
    int N, float* __restrict__ outf, u16* __restrict__ outb, u16* __restrict__ outb2,
    const float* __restrict__ bias1, const float* __restrict__ bias2,
    int m0, int n0, int mode) {
    const int tid  = threadIdx.x;
    const int wave = tid >> 6;
    const int lane = tid & 63;
    const int wm = (wave >> 1) * 64;
    const int wn = (wave & 1) * 64;
    const int lr = lane & 15;
    const int lq = lane >> 4;
    const int stg_row = lane >> 3;
    const int stg_col = (((lane & 7) ^ (lane >> 3)) << 3);

    f32x4 acc[4][4] = {};

    const int nt1 = K1 >> 6;
    const int nt2 = K2 >> 6;
    const int ntot = nt1 + nt2;

    for (int kt = 0; kt < ntot; ++kt) {
        const u16* Ap; const u16* Wp; int ld, k0;
        if (kt < nt1) { Ap = A1; Wp = W1; ld = K1; k0 = kt << 6; }
        else          { Ap = A2; Wp = W2; ld = K2; k0 = (kt - nt1) << 6; }
        #pragma unroll
        for (int i = 0; i < 4; ++i) {
            int chunk = wave * 4 + i;                 // wave-uniform
            int r = chunk * 8 + stg_row;
            load16_to_lds(Ap + (size_t)(m0 + r) * ld + (k0 + stg_col), As + chunk * 512);
            load16_to_lds(Wp + (size_t)(n0 + r) * ld + (k0 + stg_col), Bs + chunk * 512);
        }
        __syncthreads();
        #pragma unroll
        for (int kk = 0; kk < 64; kk += 32) {
            bf16x8 af[4], bfr[4];
            #pragma unroll
            for (int i = 0; i < 4; ++i) {
                int R = wm + i * 16 + lr;
                af[i] = *reinterpret_cast<const bf16x8*>(
                    &As[R * 64 + ((kk + lq * 8) ^ ((R & 7) << 3))]);
            }
            #pragma unroll
            for (int i = 0; i < 4; ++i) {
                int R = wn + i * 16 + lr;
                bfr[i] = *reinterpret_cast<const bf16x8*>(
                    &Bs[R * 64 + ((kk + lq * 8) ^ ((R & 7) << 3))]);
            }
            #pragma unroll
            for (int mi = 0; mi < 4; ++mi)
                #pragma unroll
                for (int ni = 0; ni < 4; ++ni)
                    acc[mi][ni] = __builtin_amdgcn_mfma_f32_16x16x32_bf16(
                        af[mi], bfr[ni], acc[mi][ni], 0, 0, 0);
        }
        __syncthreads();
    }

    if (mode == 8) {                      // transposed store (square 2048 out)
        #pragma unroll
        for (int mi = 0; mi < 4; ++mi) {
            #pragma unroll
            for (int ni = 0; ni < 4; ++ni) {
                int row = m0 + wm + mi * 16 + lq * 4;
                int col = n0 + wn + ni * 16 + lr;
                ushort4 v;
                v.x = f2bf(acc[mi][ni][0]); v.y = f2bf(acc[mi][ni][1]);
                v.z = f2bf(acc[mi][ni][2]); v.w = f2bf(acc[mi][ni][3]);
                *reinterpret_cast<ushort4*>(outb + (size_t)col * 2048 + row) = v;
            }
        }
        return;
    }

    #pragma unroll
    for (int mi = 0; mi < 4; ++mi) {
        #pragma unroll
        for (int ni = 0; ni < 4; ++ni) {
            #pragma unroll
            for (int j = 0; j < 4; ++j) {
                int row = m0 + wm + mi * 16 + lq * 4 + j;
                int col = n0 + wn + ni * 16 + lr;
                float v = acc[mi][ni][j];
                if (mode == 6) {
                    if (col < 2048) outb [(size_t)row * 2048 + col]        = f2bf(v);
                    else            outb2[(size_t)row * 2048 + col - 2048] = f2bf(v);
                } else if (mode == 5) {
                    float dlt = v + bias1[col];
                    float sp  = (dlt > 15.f) ? dlt : __logf(1.f + __expf(dlt));
                    outb[(size_t)row * N + col] = f2bf(bias2[col] * sp);
                } else if (mode == 2) {
                    outf[(size_t)row * N + col] = v;
                } else {
                    outb[(size_t)row * N + col] = f2bf(v);
                }
            }
        }
    }
}

// Chunked-n M-stripe-per-XCD tile map (128-tiles): XCD (q&7) owns SM m-tiles;
// n walked in chunks of CH=min(gn,8), n fastest, m next, chunk outer.
__device__ __forceinline__ void tile_coords(int q, int T, int gn, int& m0, int& n0) {
    int xcd  = q & 7;
    int loc  = q >> 3;
    int SM   = (T >> 3) / gn;            // m-tiles per XCD stripe
    int CH   = gn < 8 ? gn : 8;          // n-chunk width
    int span = SM * CH;
    int chunk = loc / span;
    int rem   = loc - chunk * span;
    int ml    = rem / CH;
    int nl    = rem - ml * CH;
    m0 = (xcd * SM + ml) * 128;
    n0 = (chunk * CH + nl) * 128;
}

// batch1: [0,256) pre1' PBt = Pb@WBb^T = P@B^T | [256,512) pre2 WXp=Db@Pb^T |
//         [512,2560) G1 split: XZ = XH @ W1^T (N=4096) -> XB / ZB
__global__ __launch_bounds__(256, 4)
void k_batch1(const u16* __restrict__ XH, const u16* __restrict__ W1,
              const u16* __restrict__ WBb, const u16* __restrict__ Pb,
              const u16* __restrict__ Db,
              u16* __restrict__ PBt, u16* __restrict__ WXp,
              u16* __restrict__ XB, u16* __restrict__ ZB) {
    __shared__ u16 As[128 * 64];
    __shared__ u16 Bs[128 * 64];
    int bid = blockIdx.x;
    int m0, n0;
    if (bid < 256) {
        tile_coords(bid, 256, 16, m0, n0);
        gemm_core(As, Bs, Pb, WBb, DI, nullptr, nullptr, 0, DI,
                  nullptr, PBt, nullptr, nullptr, nullptr, m0, n0, 0);
    } else if (bid < 512) {
        tile_coords(bid - 256, 256, 16, m0, n0);
        gemm_core(As, Bs, Db, Pb, DI, nullptr, nullptr, 0, DI,
                  nullptr, WXp, nullptr, nullptr, nullptr, m0, n0, 0);
    } else {
        tile_coords(bid - 512, 2048, 32, m0, n0);
        gemm_core(As, Bs, XH, W1, 1024, nullptr, nullptr, 0, 4096,
                  nullptr, XB, ZB, nullptr, nullptr, m0, n0, 6);
    }
}

// conv+pre3+G6: [0,256) pre3 WCBp = (PBt@WC^T)^T (mode 8) |
//               [256,1280) G6 LD = logdecay(DLT@WDT^T) (mode 5) |
//               [1280,...) depthwise causal conv (k=4) + bias + SiLU
__global__ __launch_bounds__(256, 4)
void k_conv_pre3(const u16* __restrict__ x, const float* __restrict__ w,
                 const float* __restrict__ b, u16* __restrict__ out,
                 const u16* __restrict__ PBt, const u16* __restrict__ WC,
                 u16* __restrict__ WCBp,
                 const u16* __restrict__ DLT, const u16* __restrict__ WDT,
                 const float* __restrict__ dtb, const float* __restrict__ NA,
                 u16* __restrict__ LD) {
    __shared__ u16 As[128 * 64];
    __shared__ u16 Bs[128 * 64];
    if (blockIdx.x < 256) {
        int m0, n0;
        tile_coords(blockIdx.x, 256, 16, m0, n0);
        gemm_core(As, Bs, PBt, WC, DI, nullptr, nullptr, 0, DI,
                  nullptr, WCBp, nullptr, nullptr, nullptr, m0, n0, 8);
        return;
    }
    if (blockIdx.x < 1280) {
        int m0, n0;
        tile_coords(blockIdx.x - 256, 1024, 16, m0, n0);
        gemm_core(As, Bs, DLT, WDT, 64, nullptr, nullptr, 0, DI,
                  nullptr, LD, nullptr, dtb, NA, m0, n0, 5);
        return;
    }
    int idx = (blockIdx.x - 1280) * BDIM + threadIdx.x;  // over M_ROWS*DI
    int d  = idx & (DI - 1);
    int bl = idx >> 11;
    int l  = bl & (LSEQ - 1);
    float4 wv = *reinterpret_cast<const float4*>(w + d * 4);
    float wj[4] = {wv.x, wv.y, wv.z, wv.w};
    float acc = b[d];
    #pragma unroll
    for (int j = 0; j < 4; ++j) {
        int ll = l - 3 + j;
        if (ll >= 0) acc += wj[j] * bf2f(x[(size_t)(bl - 3 + j) * DI + d]);
    }
    out[idx] = f2bf(siluf(acc));
}

// ---------------------------------------------------------------------------
// k_g36: 256x256 GEMM, [BXC | X3g] = XC @ [WCBp;WXp]^T, 4-phase K-loop.
// M=8192, N=4096, K=2048. 512 threads = 8 waves (2M x 4N). Phases per K-tile:
//  ph1: rd af(8)+bfr01(2), stage A-h0' | bar | lgkm0 | 16 MFMA ni01 kk0 | vmcnt(2) bar
//  ph2: rd bfr23(2),       stage A-h1' | bar | lgkm0 | 16 MFMA ni23 kk0 |          bar
//  ph3: rd af(8)+bfr01(2), stage B1'   | bar | lgkm0 | 16 MFMA ni01 kk32|          bar
//  ph4: rd bfr23(2),       stage B2'   | bar | lgkm0 | 16 MFMA ni23 kk32| vmcnt(2) bar
// B1 = B rows {[0,32)+[64,96)+[128,160)+[192,224)} (ni01 rows), B2 = rest.
// Guarantees: ph4-end vmcnt(2) => next tile A+B1 landed; ph1-end vmcnt(2)
// => B2 landed. Tail tile uses vmcnt(0). Epilogue fuses cumsum chunk sums.
// ---------------------------------------------------------------------------
__global__ __launch_bounds__(512, 1)
void k_g36(const u16* __restrict__ A, const u16* __restrict__ W,
           u16* __restrict__ BXC, u16* __restrict__ X3, float* __restrict__ aux1) {
    __shared__ u16 As[2][256 * 64];
    __shared__ u16 Bs[2][256 * 64];
    const int tid  = threadIdx.x;
    const int wave = tid >> 6;              // 0..7
    const int lane = tid & 63;
    const int wm = (wave >> 2) * 128;       // 2 M-waves
    const int wn = (wave & 3) * 64;         // 4 N-waves
    const int lr = lane & 15;
    const int lq = lane >> 4;
    const int stg_row = lane >> 3;
    const int stg_col = (((lane & 7) ^ (lane >> 3)) << 3);

    // tile map: 512 tiles (gm=32, gn=16). XCD (q&7) owns a 4-m-tile stripe;
    // n in chunks of 8 for L2 reuse.
    int q    = blockIdx.x;
    int xcd  = q & 7;
    int loc  = q >> 3;
    int chnk = loc >> 5;
    int rem  = loc & 31;
    int ml   = rem >> 3, nl = rem & 7;
    int m0 = (xcd * 4 + ml) * 256;
    int n0 = (chnk * 8 + nl) * 256;

    const int K = 2048;
    const int nt = 32;

    f32x4 acc[8][4] = {};

    // per-wave stage chunk ids (chunk = 8 rows)
    const int a1c0 = 2 * wave,      a1c1 = 2 * wave + 1;        // A rows 0-127
    const int a2c0 = 16 + 2 * wave, a2c1 = 17 + 2 * wave;       // A rows 128-255
    const int bk0  = ((wave >> 1) << 3) + ((wave & 1) << 1);    // B1 list
    const int b1c0 = bk0,     b1c1 = bk0 + 1;                   // B rows ni01
    const int b2c0 = bk0 + 4, b2c1 = bk0 + 5;                   // B rows ni23

    auto stgA = [&](int wb, int k0, int ch) {
        load16_to_lds(A + (size_t)(m0 + ch * 8 + stg_row) * K + (k0 + stg_col),
                      &As[wb][ch * 512]);
    };
    auto stgB = [&](int wb, int k0, int ch) {
        load16_to_lds(W + (size_t)(n0 + ch * 8 + stg_row) * K + (k0 + stg_col),
                      &Bs[wb][ch * 512]);
    };
    auto rdA8 = [&](const u16* as_, int kk, bf16x8 (&dst)[8]) {
        #pragma unroll
        for (int mi = 0; mi < 8; ++mi) {
            int R = wm + mi * 16 + lr;
            dst[mi] = *reinterpret_cast<const bf16x8*>(
                &as_[R * 64 + ((kk + lq * 8) ^ ((R & 7) << 3))]);
        }
    };
    auto rdB1 = [&](const u16* bs_, int kk, int ni, bf16x8& d) {
        int R = wn + ni * 16 + lr;
        d = *reinterpret_cast<const bf16x8*>(
            &bs_[R * 64 + ((kk + lq * 8) ^ ((R & 7) << 3))]);
    };
    auto mf8 = [&](bf16x8 (&a)[8], bf16x8 b, int ni) {
        #pragma unroll
        for (int mi = 0; mi < 8; ++mi)
            acc[mi][ni] = __builtin_amdgcn_mfma_f32_16x16x32_bf16(
                a[mi], b, acc[mi][ni], 0, 0, 0);
    };

    // prologue: tile 0 fully staged, full drain once
    stgA(0, 0, a1c0); stgA(0, 0, a1c1); stgA(0, 0, a2c0); stgA(0, 0, a2c1);
    stgB(0, 0, b1c0); stgB(0, 0, b1c1); stgB(0, 0, b2c0); stgB(0, 0, b2c1);
    asm volatile("s_waitcnt vmcnt(0)" ::: "memory");
    __builtin_amdgcn_s_barrier();

    for (int kt = 0; kt < nt; ++kt) {
        const u16* as_ = &As[kt & 1][0];
        const u16* bs_ = &Bs[kt & 1][0];
        const int  wb  = (kt + 1) & 1;
        const int  k1  = (kt + 1) << 6;
        const bool st  = (kt + 1 < nt);
        bf16x8 af[8], b0, b1, b2, b3;

        // ---- ph1: ni01 x kk0 ----
        rdA8(as_, 0, af);
        rdB1(bs_, 0, 0, b0); rdB1(bs_, 0, 1, b1);
        if (st) { stgA(wb, k1, a1c0); stgA(wb, k1, a1c1); }
        __builtin_amdgcn_s_barrier();
        asm volatile("s_waitcnt lgkmcnt(0)" ::: "memory");
        __builtin_amdgcn_sched_barrier(0);
        __builtin_amdgcn_s_setprio(1);
        mf8(af, b0, 0); mf8(af, b1, 1);
        __builtin_amdgcn_s_setprio(0);
        if (st) { asm volatile("s_waitcnt vmcnt(2)" ::: "memory"); }
        else    { asm volatile("s_waitcnt vmcnt(0)" ::: "memory"); }
        __builtin_amdgcn_s_barrier();

        // ---- ph2: ni23 x kk0 ----
        rdB1(bs_, 0, 2, b2); rdB1(bs_, 0, 3, b3);
        if (st) { stgA(wb, k1, a2c0); stgA(wb, k1, a2c1); }
        __builtin_amdgcn_s_barrier();
        asm volatile("s_waitcnt lgkmcnt(0)" ::: "memory");
        __builtin_amdgcn_sched_barrier(0);
        __builtin_amdgcn_s_setprio(1);
        mf8(af, b2, 2); mf8(af, b3, 3);
        __builtin_amdgcn_s_setprio(0);
        __builtin_amdgcn_s_barrier();

        // ---- ph3: ni01 x kk32 ----
        rdA8(as_, 32, af);
        rdB1(bs_, 32, 0, b0); rdB1(bs_, 32, 1, b1);
        if (st) { stgB(wb, k1, b1c0); stgB(wb, k1, b1c1); }
        __builtin_amdgcn_s_barrier();
        asm volatile("s_waitcnt lgkmcnt(0)" ::: "memory");
        __builtin_amdgcn_sched_barrier(0);
        __builtin_amdgcn_s_setprio(1);
        mf8(af, b0, 0); mf8(af, b1, 1);
        __builtin_amdgcn_s_setprio(0);
        __builtin_amdgcn_s_barrier();

        // ---- ph4: ni23 x kk32 ----
        rdB1(bs_, 32, 2, b2); rdB1(bs_, 32, 3, b3);
        if (st) { stgB(wb, k1, b2c0); stgB(wb, k1, b2c1); }
        __builtin_amdgcn_s_barrier();
        asm volatile("s_waitcnt lgkmcnt(0)" ::: "memory");
        __builtin_amdgcn_sched_barrier(0);
        __builtin_amdgcn_s_setprio(1);
        mf8(af, b2, 2); mf8(af, b3, 3);
        __builtin_amdgcn_s_setprio(0);
        if (st) { asm volatile("s_waitcnt vmcnt(2)" ::: "memory"); }
        __builtin_amdgcn_s_barrier();
    }

    // epilogue: store (n0 multiple of 256 -> one output) + fused cumsum
    // chunk sums for BXC blocks (block rows = 4 whole 64-row chunks).
    const bool isB = (n0 < 2048);
    u16* ob = isB ? BXC : X3;
    const int nb = n0 & 2047;
    float cs[2][4] = {};
    #pragma unroll
    for (int mi = 0; mi < 8; ++mi)
        #pragma unroll
        for (int ni = 0; ni < 4; ++ni)
            #pragma unroll
            for (int j = 0; j < 4; ++j) {
                int row = m0 + wm + mi * 16 + lq * 4 + j;
                int col = nb + wn + ni * 16 + lr;
                u16 r = f2bf(acc[mi][ni][j]);
                ob[(size_t)row * 2048 + col] = r;
                if (isB) cs[mi >> 2][ni] += bf2f(r);
            }
    if (isB) {
        #pragma unroll
        for (int g = 0; g < 2; ++g)
            #pragma unroll
            for (int ni = 0; ni < 4; ++ni) {
                float v = cs[g][ni];
                v += __shfl_xor(v, 16);
                v += __shfl_xor(v, 32);
                if (lq == 0) {
                    int rowbase = m0 + wm + g * 64;
                    int bb = rowbase >> 12;
                    int cc = (rowbase & (LSEQ - 1)) >> 6;
                    int col = nb + wn + ni * 16 + lr;
                    aux1[(size_t)(bb * NCH + cc) * DI + col] = v;
                }
            }
    }
}

// single GEMM wrapper (G7): grid dim3(gn, gm)
template <int MODE>
__global__ __launch_bounds__(256, 4)
void k_gemm(const u16* __restrict__ A1, const u16* __restrict__ W1, int K1,
            const u16* __restrict__ A2, const u16* __restrict__ W2, int K2,
            int N, float* __restrict__ outf, u16* __restrict__ outb) {
    __shared__ u16 As[128 * 64];
    __shared__ u16 Bs[128 * 64];
    int bid = blockIdx.x + gridDim.x * blockIdx.y;
    int m0, n0;
    tile_coords(bid, gridDim.x * gridDim.y, gridDim.x, m0, n0);
    gemm_core(As, Bs, A1, W1, K1, A2, W2, K2, N,
              outf, outb, nullptr, nullptr, nullptr, m0, n0, MODE);
}

// ---------------------------------------------------------------------------
// fused cumsum fold+add + scan chunk pass: X3 = cumsum(BXC) + X3g (in place),
// then scan_p1 on the rounded X3 values.
// thread layout: t = ((b*NCH + c)*DI + s); NCH*DI = 2^17
// ---------------------------------------------------------------------------
__global__ void k_cs23_scan1(const u16* __restrict__ Bx, const float* __restrict__ aux,
                             u16* x3, const u16* __restrict__ ld_,
                             float* __restrict__ auxA, float* __restrict__ auxS) {
    int t = blockIdx.x * BDIM + threadIdx.x;
    int s = t & (DI - 1);
    int c = (t >> 11) & (NCH - 1);
    int b = t >> 17;
    float run = 0.f;
    for (int j = 0; j < c; ++j) run += aux[(b * NCH + j) * DI + s];   // fold p2
    size_t base = ((size_t)(b * LSEQ + c * CLEN) * DI) + s;
    float ap = 1.f, sc = 0.f;
    for (int i = 0; i < CLEN; ++i) {
        size_t ix = base + (size_t)i * DI;
        run += bf2f(Bx[ix]);
        u16 xb = f2bf(run + bf2f(x3[ix]));
        x3[ix] = xb;
        float a = __expf(bf2f(ld_[ix]));
        sc = fmaf(a, sc, bf2f(xb));            // identical to rounded re-read
        ap *= a;
    }
    auxA[t] = ap; auxS[t] = sc;
}

// ---------------------------------------------------------------------------
// selective scan final pass: fold carry + x4 = s + u*D_ss ; out = x4*silu(z)
// ---------------------------------------------------------------------------
__global__ void k_scan_p23(const u16* __restrict__ ld_, const u16* __restrict__ u,
                           const float* __restrict__ auxA, const float* __restrict__ auxS,
                           const u16* __restrict__ z, const float* __restrict__ Dss,
                           u16* __restrict__ outb) {
    int t = blockIdx.x * BDIM + threadIdx.x;
    int d = t & (DI - 1);
    int c = (t >> 11) & (NCH - 1);
    int b = t >> 17;
    float s = 0.f;
    for (int j = 0; j < c; ++j) {                                    // fold p2
        int i = (b * NCH + j) * DI + d;
        s = fmaf(auxA[i], s, auxS[i]);
    }
    size_t base = ((size_t)(b * LSEQ + c * CLEN) * DI) + d;
    float dss = Dss[d];
    for (int i = 0; i < CLEN; ++i) {
        size_t ix = base + (size_t)i * DI;
        float a = __expf(bf2f(ld_[ix]));
        float uu = bf2f(u[ix]);
        s = fmaf(a, s, uu);
        float x4 = s + uu * dss;
        float zz = bf2f(z[ix]);
        outb[ix] = f2bf(x4 * siluf(zz));
    }
}

// ---------------------------------------------------------------------------
extern "C" void kernel_launch(void* const* d_in, const int* in_sizes, int n_in,
                              void* d_out, int out_size, void* d_ws, size_t ws_size,
                              hipStream_t stream) {
    const float* hs     = (const float*)d_in[0];
    const float* delta  = (const float*)d_in[1];
    const float* inproj = (const float*)d_in[2];
    const float* convw  = (const float*)d_in[3];
    const float* convb  = (const float*)d_in[4];
    const float* Areal  = (const float*)d_in[5];
    const float* Bw     = (const float*)d_in[6];
    const float* Cw     = (const float*)d_in[7];
    const float* Dw     = (const float*)d_in[8];
    const float* dtw    = (const float*)d_in[9];
    const float* dtb    = (const float*)d_in[10];
    const float* Alog   = (const float*)d_in[11];
    const float* Dss    = (const float*)d_in[12];
    const float* outw   = (const float*)d_in[13];
    float* out = (float*)d_out;

    // ---- liveness-overlaid workspace layout (~241 MB total) ----
    const size_t SZ_ACT = (size_t)M_ROWS * DI * 2;     // 32 MB
    char* p = (char*)d_ws;
    u16* ZB  = (u16*)p; p += SZ_ACT;                   // z: batch1 -> scan_p23
    u16* XB  = (u16*)p;                                // x: batch1 -> conv
    u16* X3  = XB;      p += SZ_ACT;                   // X3g: g36 -> cs23_scan1 (in place) -> scan_p23
    u16* XC  = (u16*)p;                                // conv out -> g36
    u16* OUT = XC;      p += SZ_ACT;                   // scan_p23 out -> G7
    u16* BXC = (u16*)p; p += SZ_ACT;                   // g36 out -> cumsum
    u16* WCBp= (u16*)p;                                // C·B·P^T (8MB)
    u16* WXp = WCBp + (size_t)DI * DI;                 // (I+D_w)@P^T, CONTIGUOUS after WCBp
                        p += SZ_ACT;                   // 32MB slot holds both (16MB used)
    u16* XH  = (u16*)p;                                // hs bf16 (dead after batch1)
    u16* LD  = XH;                                     // log-decay overlays XH+W1+WBb (32MB)
                        p += (size_t)M_ROWS * 1024 * 2;   // 16 MB
    u16* W1  = (u16*)p; p += (size_t)4096 * 1024 * 2;     // 8 MB
    u16* WBb = (u16*)p; p += (size_t)DI * DI * 2;         // 8 MB  bf16(B_w)
    u16* WC  = (u16*)p; p += (size_t)DI * DI * 2;         // 8 MB  bf16(C_w)
    u16* Pb  = (u16*)p; p += (size_t)DI * DI * 2;         // 8 MB  bf16(I+A_real)
    u16* Db  = (u16*)p; p += (size_t)DI * DI * 2;         // 8 MB  bf16(I+D_w)
    u16* PBt = (u16*)p; p += (size_t)DI * DI * 2;         // 8 MB  P @ B^T
    p += (size_t)DI * DI * 2;                             // (old WXp slot, unused)
    u16* WO  = (u16*)p; p += (size_t)1024 * DI * 2;       // 4 MB
    u16* WDT = (u16*)p; p += (size_t)DI * 64 * 2;
    u16* DLT = (u16*)p; p += (size_t)M_ROWS * 64 * 2;
    float* aux1 = (float*)p; p += (size_t)2 * NCH * DI * 4;   // 1 MB
    float* auxA = (float*)p; p += (size_t)2 * NCH * DI * 4;
    float* auxS = (float*)p; p += (size_t)2 * NCH * DI * 4;
    float* NA   = (float*)p; p += (size_t)DI * 4;             // -exp(A_log)

    // 1) all converts (incl. +I for Pb/Db, NA tail)
    k_cvt_all<<<31362, BDIM, 0, stream>>>(hs, inproj, Bw, Cw, outw, delta, dtw,
                                          Areal, Dw, Alog,
                                          XH, W1, WBb, WC, WO, DLT, WDT, Pb, Db, NA);
    // 2) pre1' (PBt) + pre2 (WXp) + G1(split)
    k_batch1<<<2560, BDIM, 0, stream>>>(XH, W1, WBb, Pb, Db, PBt, WXp, XB, ZB);
    // 3) pre3 (WCBp) + G6 (LD) + conv + SiLU
    k_conv_pre3<<<1280 + (M_ROWS * DI) / BDIM, BDIM, 0, stream>>>(
        XB, convw, convb, XC, PBt, WC, WCBp, DLT, WDT, dtb, NA, LD);
    // 4) G36 4-phase: [BXC|X3g] = XC@[WCBp;WXp]^T ; fused cumsum chunk sums
    k_g36<<<512, 512, 0, stream>>>(XC, WCBp, BXC, X3, aux1);
    // 5) fused cumsum fold+add (X3 in place) + scan chunk pass
    k_cs23_scan1<<<(2 * NCH * DI) / BDIM, BDIM, 0, stream>>>(BXC, aux1, X3,
                                                             LD, auxA, auxS);
    // 6) scan final pass -> OUT (overlays dead XC)
    k_scan_p23<<<(2 * NCH * DI) / BDIM, BDIM, 0, stream>>>(LD, X3, auxA, auxS,
                                                           ZB, Dss, OUT);
    // 7) G7: out = OUT @ out_proj^T (f32)
    k_gemm<2><<<dim3(8, 64), BDIM, 0, stream>>>(OUT, WO, DI, nullptr, nullptr, 0,
                                                1024, out, nullptr);
}

// Round 9
// 599.174 us; speedup vs baseline: 1.0834x; 1.0834x over previous
//
#include <hip/hip_runtime.h>
#include <cstdint>
#include <cstddef>

// ---------------------------------------------------------------------------
// Mamba3Block on MI355X. B=2, L=4096, D_MODEL=1024, D_INNER=D_STATE=2048.
// R15: (a) g36 K-loop reverted to the R12 2-phase counted-vmcnt form (126.7us
// verified; R14's 4-phase split = 8 barriers/tile at 1 block/CU regressed to
// 147us). R14's fused-cumsum epilogue kept (verified correct). (b) G1 ported
// to the same 256x256 counted-vmcnt core: k_g1pre = pre1+pre2 (128 blocks,
// scheduled FIRST for packing) + G1 (512 blocks). batch1 deleted.
// 7 dispatches.
// Kept: chunked-n XCD map for 128x128 cores, merged [WCBp;WXp], cumsum-
// commute algebra, fast softplus + NA precompute, cs23+scan1 fusion.
// ---------------------------------------------------------------------------

typedef unsigned short u16;                 // bf16 storage (bit pattern)
typedef __bf16 bf16x8 __attribute__((ext_vector_type(8)));
typedef float  f32x4  __attribute__((ext_vector_type(4)));

#define BDIM 256
#define M_ROWS 8192            // B*L
#define LSEQ   4096
#define DI     2048            // d_inner / d_state
#define NCH    64              // scan chunks
#define CLEN   64              // LSEQ / NCH

__device__ __forceinline__ float bf2f(u16 h) {
    return __uint_as_float(((unsigned int)h) << 16);
}
__device__ __forceinline__ u16 f2bf(float f) {
    unsigned int u = __float_as_uint(f);
    u = u + 0x7fffu + ((u >> 16) & 1u);     // RNE
    return (u16)(u >> 16);
}
__device__ __forceinline__ float siluf(float v) { return v / (1.0f + __expf(-v)); }

__device__ __forceinline__ void load16_to_lds(const u16* g, u16* l) {
    __builtin_amdgcn_global_load_lds((const __attribute__((address_space(1))) void*)g,
                                     (__attribute__((address_space(3))) void*)l,
                                     16, 0, 0);
}

// ---------------------------------------------------------------------------
// fused f32 -> bf16 convert of ALL inputs (1 launch), incl. +I diag segments,
// plus tail segment: NA[d] = -exp(A_log[d]) (f32, 2048 elems).
// ---------------------------------------------------------------------------
__global__ void k_cvt_all(const float* __restrict__ hs, const float* __restrict__ inproj,
                          const float* __restrict__ Bw, const float* __restrict__ Cw,
                          const float* __restrict__ outw, const float* __restrict__ delta,
                          const float* __restrict__ dtw, const float* __restrict__ Areal,
                          const float* __restrict__ Dw, const float* __restrict__ Alog,
                          u16* __restrict__ XH, u16* __restrict__ W1, u16* __restrict__ WBb,
                          u16* __restrict__ WC, u16* __restrict__ WO, u16* __restrict__ DLT,
                          u16* __restrict__ WDT, u16* __restrict__ Pb, u16* __restrict__ Db,
                          float* __restrict__ NA) {
    long i = (long)(blockIdx.x * BDIM + threadIdx.x) * 4;
    if (i >= 32112640L) {                       // NA tail: 2048 f32
        long j = i - 32112640L;
        if (j < 2048) {
            float4 v = *reinterpret_cast<const float4*>(Alog + j);
            float4 o = {-__expf(v.x), -__expf(v.y), -__expf(v.z), -__expf(v.w)};
            *reinterpret_cast<float4*>(NA + j) = o;
        }
        return;
    }
    const float* src; u16* dst; long off; bool diag = false;
    if      (i <  8388608L) { src = hs;     dst = XH;  off = 0L; }
    else if (i < 12582912L) { src = inproj; dst = W1;  off = 8388608L; }
    else if (i < 16777216L) { src = Bw;     dst = WBb; off = 12582912L; }
    else if (i < 20971520L) { src = Cw;     dst = WC;  off = 16777216L; }
    else if (i < 23068672L) { src = outw;   dst = WO;  off = 20971520L; }
    else if (i < 23592960L) { src = delta;  dst = DLT; off = 23068672L; }
    else if (i < 23724032L) { src = dtw;    dst = WDT; off = 23592960L; }
    else if (i < 27918336L) { src = Areal;  dst = Pb;  off = 23724032L; diag = true; }
    else                    { src = Dw;     dst = Db;  off = 27918336L; diag = true; }
    long j = i - off;
    float4 v = *reinterpret_cast<const float4*>(src + j);
    if (diag) {
        int r = (int)(j >> 11), c = (int)(j & 2047);
        if (r >= c && r < c + 4) (&v.x)[r - c] += 1.0f;
    }
    ushort2 a = {f2bf(v.x), f2bf(v.y)};
    ushort2 b = {f2bf(v.z), f2bf(v.w)};
    *reinterpret_cast<ushort2*>(dst + j)     = a;
    *reinterpret_cast<ushort2*>(dst + j + 2) = b;
}

// ---------------------------------------------------------------------------
// 128x128 GEMM tile core (proven): C_tile = A1*W1^T (+ A2*W2^T).
// LDS XOR-swizzle (r,c) -> r*64 + (c ^ ((r&7)*8)); staging = global_load_lds.
// mode 0: store bf16; 2: store f32; 5: log-decay bf16; 6: split; 8: transposed
// ---------------------------------------------------------------------------
__device__ __forceinline__ void gemm_core(
    u16* As, u16* Bs,
    const u16* __restrict__ A1, const u16* __restrict__ W1, int K1,
    const u16* __restrict__ A2, const u16* __restrict__ W2, int K2,
    int N, float* __restrict__ outf, u16* __restrict__ outb, u16* __restrict__ outb2,
    const float* __restrict__ bias1, const float* __restrict__ bias2,
    int m0, int n0, int mode) {
    const int tid  = threadIdx.x;
    const int wave = tid >> 6;
    const int lane = tid & 63;
    const int wm = (wave >> 1) * 64;
    const int wn = (wave & 1) * 64;
    const int lr = lane & 15;
    const int lq = lane >> 4;
    const int stg_row = lane >> 3;
    const int stg_col = (((lane & 7) ^ (lane >> 3)) << 3);

    f32x4 acc[4][4] = {};

    const int nt1 = K1 >> 6;
    const int nt2 = K2 >> 6;
    const int ntot = nt1 + nt2;

    for (int kt = 0; kt < ntot; ++kt) {
        const u16* Ap; const u16* Wp; int ld, k0;
        if (kt < nt1) { Ap = A1; Wp = W1; ld = K1; k0 = kt << 6; }
        else          { Ap = A2; Wp = W2; ld = K2; k0 = (kt - nt1) << 6; }
        #pragma unroll
        for (int i = 0; i < 4; ++i) {
            int chunk = wave * 4 + i;                 // wave-uniform
            int r = chunk * 8 + stg_row;
            load16_to_lds(Ap + (size_t)(m0 + r) * ld + (k0 + stg_col), As + chunk * 512);
            load16_to_lds(Wp + (size_t)(n0 + r) * ld + (k0 + stg_col), Bs + chunk * 512);
        }
        __syncthreads();
        #pragma unroll
        for (int kk = 0; kk < 64; kk += 32) {
            bf16x8 af[4], bfr[4];
            #pragma unroll
            for (int i = 0; i < 4; ++i) {
                int R = wm + i * 16 + lr;
                af[i] = *reinterpret_cast<const bf16x8*>(
                    &As[R * 64 + ((kk + lq * 8) ^ ((R & 7) << 3))]);
            }
            #pragma unroll
            for (int i = 0; i < 4; ++i) {
                int R = wn + i * 16 + lr;
                bfr[i] = *reinterpret_cast<const bf16x8*>(
                    &Bs[R * 64 + ((kk + lq * 8) ^ ((R & 7) << 3))]);
            }
            #pragma unroll
            for (int mi = 0; mi < 4; ++mi)
                #pragma unroll
                for (int ni = 0; ni < 4; ++ni)
                    acc[mi][ni] = __builtin_amdgcn_mfma_f32_16x16x32_bf16(
                        af[mi], bfr[ni], acc[mi][ni], 0, 0, 0);
        }
        __syncthreads();
    }

    if (mode == 8) {                      // transposed store (square 2048 out)
        #pragma unroll
        for (int mi = 0; mi < 4; ++mi) {
            #pragma unroll
            for (int ni = 0; ni < 4; ++ni) {
                int row = m0 + wm + mi * 16 + lq * 4;
                int col = n0 + wn + ni * 16 + lr;
                ushort4 v;
                v.x = f2bf(acc[mi][ni][0]); v.y = f2bf(acc[mi][ni][1]);
                v.z = f2bf(acc[mi][ni][2]); v.w = f2bf(acc[mi][ni][3]);
                *reinterpret_cast<ushort4*>(outb + (size_t)col * 2048 + row) = v;
            }
        }
        return;
    }

    #pragma unroll
    for (int mi = 0; mi < 4; ++mi) {
        #pragma unroll
        for (int ni = 0; ni < 4; ++ni) {
            #pragma unroll
            for (int j = 0; j < 4; ++j) {
                int row = m0 + wm + mi * 16 + lq * 4 + j;
                int col = n0 + wn + ni * 16 + lr;
                float v = acc[mi][ni][j];
                if (mode == 6) {
                    if (col < 2048) outb [(size_t)row * 2048 + col]        = f2bf(v);
                    else            outb2[(size_t)row * 2048 + col - 2048] = f2bf(v);
                } else if (mode == 5) {
                    float dlt = v + bias1[col];
                    float sp  = (dlt > 15.f) ? dlt : __logf(1.f + __expf(dlt));
                    outb[(size_t)row * N + col] = f2bf(bias2[col] * sp);
                } else if (mode == 2) {
                    outf[(size_t)row * N + col] = v;
                } else {
                    outb[(size_t)row * N + col] = f2bf(v);
                }
            }
        }
    }
}

// Chunked-n M-stripe-per-XCD tile map (128-tiles): XCD (q&7) owns SM m-tiles;
// n walked in chunks of CH=min(gn,8), n fastest, m next, chunk outer.
__device__ __forceinline__ void tile_coords(int q, int T, int gn, int& m0, int& n0) {
    int xcd  = q & 7;
    int loc  = q >> 3;
    int SM   = (T >> 3) / gn;            // m-tiles per XCD stripe
    int CH   = gn < 8 ? gn : 8;          // n-chunk width
    int span = SM * CH;
    int chunk = loc / span;
    int rem   = loc - chunk * span;
    int ml    = rem / CH;
    int nl    = rem - ml * CH;
    m0 = (xcd * SM + ml) * 128;
    n0 = (chunk * CH + nl) * 128;
}

// ---------------------------------------------------------------------------
// Shared 256x256 deep-pipelined K-loop (R12 form, verified 1084 TF):
// double-buffered LDS, raw s_barrier + counted vmcnt(8); prefetch tile kt+2
// stays in flight across barriers. Accumulation order = 128x128 core.
// ---------------------------------------------------------------------------
__device__ __forceinline__ void g256_loop(
    const u16* __restrict__ A, const u16* __restrict__ Wt, int K, int nt,
    int m0, int n0, u16* As0, u16* As1, u16* Bs0, u16* Bs1,
    f32x4 (&acc)[8][4]) {
    const int tid  = threadIdx.x;
    const int wave = tid >> 6;              // 0..7
    const int lane = tid & 63;
    const int wm = (wave >> 2) * 128;       // 2 M-waves
    const int wn = (wave & 3) * 64;         // 4 N-waves
    const int lr = lane & 15;
    const int lq = lane >> 4;
    const int stg_row = lane >> 3;
    const int stg_col = (((lane & 7) ^ (lane >> 3)) << 3);

    auto stage = [&](int kt) {
        u16* da = (kt & 1) ? As1 : As0;
        u16* db = (kt & 1) ? Bs1 : Bs0;
        int k0 = kt << 6;
        #pragma unroll
        for (int i = 0; i < 4; ++i) {
            int ch = wave * 4 + i;          // wave-uniform
            int r  = ch * 8 + stg_row;
            load16_to_lds(A  + (size_t)(m0 + r) * K + (k0 + stg_col), da + ch * 512);
            load16_to_lds(Wt + (size_t)(n0 + r) * K + (k0 + stg_col), db + ch * 512);
        }
    };

    stage(0);
    stage(1);
    asm volatile("s_waitcnt vmcnt(8)" ::: "memory");   // tile 0 landed
    __builtin_amdgcn_s_barrier();

    for (int kt = 0; kt < nt; ++kt) {
        const u16* as_ = (kt & 1) ? As1 : As0;
        const u16* bs_ = (kt & 1) ? Bs1 : Bs0;
        bf16x8 af[8], bfr[4];
        #pragma unroll
        for (int mi = 0; mi < 8; ++mi) {
            int R = wm + mi * 16 + lr;
            af[mi] = *reinterpret_cast<const bf16x8*>(
                &as_[R * 64 + ((lq * 8) ^ ((R & 7) << 3))]);
        }
        #pragma unroll
        for (int ni = 0; ni < 4; ++ni) {
            int R = wn + ni * 16 + lr;
            bfr[ni] = *reinterpret_cast<const bf16x8*>(
                &bs_[R * 64 + ((lq * 8) ^ ((R & 7) << 3))]);
        }
        #pragma unroll
        for (int mi = 0; mi < 8; ++mi)
            #pragma unroll
            for (int ni = 0; ni < 4; ++ni)
                acc[mi][ni] = __builtin_amdgcn_mfma_f32_16x16x32_bf16(
                    af[mi], bfr[ni], acc[mi][ni], 0, 0, 0);
        bf16x8 af2[8], bfr2[4];
        #pragma unroll
        for (int mi = 0; mi < 8; ++mi) {
            int R = wm + mi * 16 + lr;
            af2[mi] = *reinterpret_cast<const bf16x8*>(
                &as_[R * 64 + ((32 + lq * 8) ^ ((R & 7) << 3))]);
        }
        #pragma unroll
        for (int ni = 0; ni < 4; ++ni) {
            int R = wn + ni * 16 + lr;
            bfr2[ni] = *reinterpret_cast<const bf16x8*>(
                &bs_[R * 64 + ((32 + lq * 8) ^ ((R & 7) << 3))]);
        }
        asm volatile("s_waitcnt lgkmcnt(0)" ::: "memory");  // my reads done
        __builtin_amdgcn_sched_barrier(0);
        __builtin_amdgcn_s_barrier();           // all waves done reading buf
        if (kt + 2 < nt) stage(kt + 2);         // overwrite released buf
        __builtin_amdgcn_s_setprio(1);
        #pragma unroll
        for (int mi = 0; mi < 8; ++mi)
            #pragma unroll
            for (int ni = 0; ni < 4; ++ni)
                acc[mi][ni] = __builtin_amdgcn_mfma_f32_16x16x32_bf16(
                    af2[mi], bfr2[ni], acc[mi][ni], 0, 0, 0);
        __builtin_amdgcn_s_setprio(0);
        if (kt + 2 < nt) {
            asm volatile("s_waitcnt vmcnt(8)" ::: "memory");  // tile kt+1 landed
        } else if (kt + 1 < nt) {
            asm volatile("s_waitcnt vmcnt(0)" ::: "memory");
        }
        __builtin_amdgcn_s_barrier();
    }
}

// ---------------------------------------------------------------------------
// k_g1pre: pre1+pre2 (q<128, K=2048) + G1 (q>=128, K=1024), 256x256 core.
// pre blocks first (longest) for round packing. G1 split-stores XB/ZB.
// ---------------------------------------------------------------------------
__global__ __launch_bounds__(512, 2)
void k_g1pre(const u16* __restrict__ XH, const u16* __restrict__ W1,
             const u16* __restrict__ Pb, const u16* __restrict__ WBb,
             const u16* __restrict__ Db,
             u16* __restrict__ XB, u16* __restrict__ ZB,
             u16* __restrict__ PBt, u16* __restrict__ WXp) {
    __shared__ u16 As[2][256 * 64];
    __shared__ u16 Bs[2][256 * 64];
    int q = blockIdx.x;
    const u16 *A, *W; int K, nt, m0, n0, nb; u16* ob;
    if (q < 128) {                      // pre1 / pre2: 2048x2048, 8x8 tiles
        int p = q & 63;
        m0 = (p & 7) * 256; n0 = (p >> 3) * 256; nb = n0;
        K = 2048; nt = 32;
        if (q < 64) { A = Pb; W = WBb; ob = PBt; }
        else        { A = Db; W = Pb;  ob = WXp; }
    } else {                            // G1: M=8192 N=4096 K=1024
        int p = q - 128;
        int xcd = p & 7, loc = p >> 3;
        int chnk = loc >> 5, rem = loc & 31;
        int ml = rem >> 3, nl = rem & 7;
        m0 = (xcd * 4 + ml) * 256;
        n0 = (chnk * 8 + nl) * 256;
        K = 1024; nt = 16;
        A = XH; W = W1;
        ob = (n0 < 2048) ? XB : ZB;     // whole 256-block goes to one side
        nb = n0 & 2047;
    }
    f32x4 acc[8][4] = {};
    g256_loop(A, W, K, nt, m0, n0, &As[0][0], &As[1][0], &Bs[0][0], &Bs[1][0], acc);

    const int tid  = threadIdx.x;
    const int wave = tid >> 6;
    const int lane = tid & 63;
    const int wm = (wave >> 2) * 128;
    const int wn = (wave & 3) * 64;
    const int lr = lane & 15;
    const int lq = lane >> 4;
    #pragma unroll
    for (int mi = 0; mi < 8; ++mi)
        #pragma unroll
        for (int ni = 0; ni < 4; ++ni)
            #pragma unroll
            for (int j = 0; j < 4; ++j) {
                int row = m0 + wm + mi * 16 + lq * 4 + j;
                int col = nb + wn + ni * 16 + lr;
                ob[(size_t)row * 2048 + col] = f2bf(acc[mi][ni][j]);
            }
}

// ---------------------------------------------------------------------------
// k_g36: [BXC | X3g] = XC @ [WCBp;WXp]^T (M=8192 N=4096 K=2048), 256x256
// core + fused cumsum chunk sums in epilogue (BXC rows = whole 64-chunks).
// ---------------------------------------------------------------------------
__global__ __launch_bounds__(512, 2)
void k_g36(const u16* __restrict__ A, const u16* __restrict__ W,
           u16* __restrict__ BXC, u16* __restrict__ X3, float* __restrict__ aux1) {
    __shared__ u16 As[2][256 * 64];
    __shared__ u16 Bs[2][256 * 64];
    int q    = blockIdx.x;
    int xcd  = q & 7;
    int loc  = q >> 3;
    int chnk = loc >> 5;
    int rem  = loc & 31;
    int ml   = rem >> 3, nl = rem & 7;
    int m0 = (xcd * 4 + ml) * 256;
    int n0 = (chnk * 8 + nl) * 256;

    f32x4 acc[8][4] = {};
    g256_loop(A, W, 2048, 32, m0, n0, &As[0][0], &As[1][0], &Bs[0][0], &Bs[1][0], acc);

    const int tid  = threadIdx.x;
    const int wave = tid >> 6;
    const int lane = tid & 63;
    const int wm = (wave >> 2) * 128;
    const int wn = (wave & 3) * 64;
    const int lr = lane & 15;
    const int lq = lane >> 4;
    const bool isB = (n0 < 2048);
    u16* ob = isB ? BXC : X3;
    const int nb = n0 & 2047;
    float cs[2][4] = {};
    #pragma unroll
    for (int mi = 0; mi < 8; ++mi)
        #pragma unroll
        for (int ni = 0; ni < 4; ++ni)
            #pragma unroll
            for (int j = 0; j < 4; ++j) {
                int row = m0 + wm + mi * 16 + lq * 4 + j;
                int col = nb + wn + ni * 16 + lr;
                u16 r = f2bf(acc[mi][ni][j]);
                ob[(size_t)row * 2048 + col] = r;
                if (isB) cs[mi >> 2][ni] += bf2f(r);
            }
    if (isB) {
        #pragma unroll
        for (int g = 0; g < 2; ++g)
            #pragma unroll
            for (int ni = 0; ni < 4; ++ni) {
                float v = cs[g][ni];
                v += __shfl_xor(v, 16);
                v += __shfl_xor(v, 32);
                if (lq == 0) {
                    int rowbase = m0 + wm + g * 64;
                    int bb = rowbase >> 12;
                    int cc = (rowbase & (LSEQ - 1)) >> 6;
                    int col = nb + wn + ni * 16 + lr;
                    aux1[(size_t)(bb * NCH + cc) * DI + col] = v;
                }
            }
    }
}

// conv+pre3+G6: [0,256) pre3 WCBp = (PBt@WC^T)^T (mode 8) |
//               [256,1280) G6 LD = logdecay(DLT@WDT^T) (mode 5) |
//               [1280,...) depthwise causal conv (k=4) + bias + SiLU
__global__ __launch_bounds__(256, 4)
void k_conv_pre3(const u16* __restrict__ x, const float* __restrict__ w,
                 const float* __restrict__ b, u16* __restrict__ out,
                 const u16* __restrict__ PBt, const u16* __restrict__ WC,
                 u16* __restrict__ WCBp,
                 const u16* __restrict__ DLT, const u16* __restrict__ WDT,
                 const float* __restrict__ dtb, const float* __restrict__ NA,
                 u16* __restrict__ LD) {
    __shared__ u16 As[128 * 64];
    __shared__ u16 Bs[128 * 64];
    if (blockIdx.x < 256) {
        int m0, n0;
        tile_coords(blockIdx.x, 256, 16, m0, n0);
        gemm_core(As, Bs, PBt, WC, DI, nullptr, nullptr, 0, DI,
                  nullptr, WCBp, nullptr, nullptr, nullptr, m0, n0, 8);
        return;
    }
    if (blockIdx.x < 1280) {
        int m0, n0;
        tile_coords(blockIdx.x - 256, 1024, 16, m0, n0);
        gemm_core(As, Bs, DLT, WDT, 64, nullptr, nullptr, 0, DI,
                  nullptr, LD, nullptr, dtb, NA, m0, n0, 5);
        return;
    }
    int idx = (blockIdx.x - 1280) * BDIM + threadIdx.x;  // over M_ROWS*DI
    int d  = idx & (DI - 1);
    int bl = idx >> 11;
    int l  = bl & (LSEQ - 1);
    float4 wv = *reinterpret_cast<const float4*>(w + d * 4);
    float wj[4] = {wv.x, wv.y, wv.z, wv.w};
    float acc = b[d];
    #pragma unroll
    for (int j = 0; j < 4; ++j) {
        int ll = l - 3 + j;
        if (ll >= 0) acc += wj[j] * bf2f(x[(size_t)(bl - 3 + j) * DI + d]);
    }
    out[idx] = f2bf(siluf(acc));
}

// single GEMM wrapper (G7): grid dim3(gn, gm)
template <int MODE>
__global__ __launch_bounds__(256, 4)
void k_gemm(const u16* __restrict__ A1, const u16* __restrict__ W1, int K1,
            const u16* __restrict__ A2, const u16* __restrict__ W2, int K2,
            int N, float* __restrict__ outf, u16* __restrict__ outb) {
    __shared__ u16 As[128 * 64];
    __shared__ u16 Bs[128 * 64];
    int bid = blockIdx.x + gridDim.x * blockIdx.y;
    int m0, n0;
    tile_coords(bid, gridDim.x * gridDim.y, gridDim.x, m0, n0);
    gemm_core(As, Bs, A1, W1, K1, A2, W2, K2, N,
              outf, outb, nullptr, nullptr, nullptr, m0, n0, MODE);
}

// ---------------------------------------------------------------------------
// fused cumsum fold+add + scan chunk pass: X3 = cumsum(BXC) + X3g (in place),
// then scan_p1 on the rounded X3 values.
// thread layout: t = ((b*NCH + c)*DI + s); NCH*DI = 2^17
// ---------------------------------------------------------------------------
__global__ void k_cs23_scan1(const u16* __restrict__ Bx, const float* __restrict__ aux,
                             u16* x3, const u16* __restrict__ ld_,
                             float* __restrict__ auxA, float* __restrict__ auxS) {
    int t = blockIdx.x * BDIM + threadIdx.x;
    int s = t & (DI - 1);
    int c = (t >> 11) & (NCH - 1);
    int b = t >> 17;
    float run = 0.f;
    for (int j = 0; j < c; ++j) run += aux[(b * NCH + j) * DI + s];   // fold p2
    size_t base = ((size_t)(b * LSEQ + c * CLEN) * DI) + s;
    float ap = 1.f, sc = 0.f;
    for (int i = 0; i < CLEN; ++i) {
        size_t ix = base + (size_t)i * DI;
        run += bf2f(Bx[ix]);
        u16 xb = f2bf(run + bf2f(x3[ix]));
        x3[ix] = xb;
        float a = __expf(bf2f(ld_[ix]));
        sc = fmaf(a, sc, bf2f(xb));            // identical to rounded re-read
        ap *= a;
    }
    auxA[t] = ap; auxS[t] = sc;
}

// ---------------------------------------------------------------------------
// selective scan final pass: fold carry + x4 = s + u*D_ss ; out = x4*silu(z)
// ---------------------------------------------------------------------------
__global__ void k_scan_p23(const u16* __restrict__ ld_, const u16* __restrict__ u,
                           const float* __restrict__ auxA, const float* __restrict__ auxS,
                           const u16* __restrict__ z, const float* __restrict__ Dss,
                           u16* __restrict__ outb) {
    int t = blockIdx.x * BDIM + threadIdx.x;
    int d = t & (DI - 1);
    int c = (t >> 11) & (NCH - 1);
    int b = t >> 17;
    float s = 0.f;
    for (int j = 0; j < c; ++j) {                                    // fold p2
        int i = (b * NCH + j) * DI + d;
        s = fmaf(auxA[i], s, auxS[i]);
    }
    size_t base = ((size_t)(b * LSEQ + c * CLEN) * DI) + d;
    float dss = Dss[d];
    for (int i = 0; i < CLEN; ++i) {
        size_t ix = base + (size_t)i * DI;
        float a = __expf(bf2f(ld_[ix]));
        float uu = bf2f(u[ix]);
        s = fmaf(a, s, uu);
        float x4 = s + uu * dss;
        float zz = bf2f(z[ix]);
        outb[ix] = f2bf(x4 * siluf(zz));
    }
}

// ---------------------------------------------------------------------------
extern "C" void kernel_launch(void* const* d_in, const int* in_sizes, int n_in,
                              void* d_out, int out_size, void* d_ws, size_t ws_size,
                              hipStream_t stream) {
    const float* hs     = (const float*)d_in[0];
    const float* delta  = (const float*)d_in[1];
    const float* inproj = (const float*)d_in[2];
    const float* convw  = (const float*)d_in[3];
    const float* convb  = (const float*)d_in[4];
    const float* Areal  = (const float*)d_in[5];
    const float* Bw     = (const float*)d_in[6];
    const float* Cw     = (const float*)d_in[7];
    const float* Dw     = (const float*)d_in[8];
    const float* dtw    = (const float*)d_in[9];
    const float* dtb    = (const float*)d_in[10];
    const float* Alog   = (const float*)d_in[11];
    const float* Dss    = (const float*)d_in[12];
    const float* outw   = (const float*)d_in[13];
    float* out = (float*)d_out;

    // ---- liveness-overlaid workspace layout (~241 MB total) ----
    const size_t SZ_ACT = (size_t)M_ROWS * DI * 2;     // 32 MB
    char* p = (char*)d_ws;
    u16* ZB  = (u16*)p; p += SZ_ACT;                   // z: g1pre -> scan_p23
    u16* XB  = (u16*)p;                                // x: g1pre -> conv
    u16* X3  = XB;      p += SZ_ACT;                   // X3g: g36 -> cs23_scan1 (in place) -> scan_p23
    u16* XC  = (u16*)p;                                // conv out -> g36
    u16* OUT = XC;      p += SZ_ACT;                   // scan_p23 out -> G7
    u16* BXC = (u16*)p; p += SZ_ACT;                   // g36 out -> cumsum
    u16* WCBp= (u16*)p;                                // C·B·P^T (8MB)
    u16* WXp = WCBp + (size_t)DI * DI;                 // (I+D_w)@P^T, CONTIGUOUS after WCBp
                        p += SZ_ACT;                   // 32MB slot holds both (16MB used)
    u16* XH  = (u16*)p;                                // hs bf16 (dead after g1pre)
    u16* LD  = XH;                                     // log-decay overlays XH+W1+WBb (32MB)
                        p += (size_t)M_ROWS * 1024 * 2;   // 16 MB
    u16* W1  = (u16*)p; p += (size_t)4096 * 1024 * 2;     // 8 MB
    u16* WBb = (u16*)p; p += (size_t)DI * DI * 2;         // 8 MB  bf16(B_w)
    u16* WC  = (u16*)p; p += (size_t)DI * DI * 2;         // 8 MB  bf16(C_w)
    u16* Pb  = (u16*)p; p += (size_t)DI * DI * 2;         // 8 MB  bf16(I+A_real)
    u16* Db  = (u16*)p; p += (size_t)DI * DI * 2;         // 8 MB  bf16(I+D_w)
    u16* PBt = (u16*)p; p += (size_t)DI * DI * 2;         // 8 MB  P @ B^T
    p += (size_t)DI * DI * 2;                             // (old WXp slot, unused)
    u16* WO  = (u16*)p; p += (size_t)1024 * DI * 2;       // 4 MB
    u16* WDT = (u16*)p; p += (size_t)DI * 64 * 2;
    u16* DLT = (u16*)p; p += (size_t)M_ROWS * 64 * 2;
    float* aux1 = (float*)p; p += (size_t)2 * NCH * DI * 4;   // 1 MB
    float* auxA = (float*)p; p += (size_t)2 * NCH * DI * 4;
    float* auxS = (float*)p; p += (size_t)2 * NCH * DI * 4;
    float* NA   = (float*)p; p += (size_t)DI * 4;             // -exp(A_log)

    // 1) all converts (incl. +I for Pb/Db, NA tail)
    k_cvt_all<<<31362, BDIM, 0, stream>>>(hs, inproj, Bw, Cw, outw, delta, dtw,
                                          Areal, Dw, Alog,
                                          XH, W1, WBb, WC, WO, DLT, WDT, Pb, Db, NA);
    // 2) pre1'+pre2 (128 blocks, first) + G1 (512 blocks), 256x256 core
    k_g1pre<<<640, 512, 0, stream>>>(XH, W1, Pb, WBb, Db, XB, ZB, PBt, WXp);
    // 3) pre3 (WCBp) + G6 (LD) + conv + SiLU
    k_conv_pre3<<<1280 + (M_ROWS * DI) / BDIM, BDIM, 0, stream>>>(
        XB, convw, convb, XC, PBt, WC, WCBp, DLT, WDT, dtb, NA, LD);
    // 4) G36: [BXC|X3g] = XC@[WCBp;WXp]^T ; fused cumsum chunk sums
    k_g36<<<512, 512, 0, stream>>>(XC, WCBp, BXC, X3, aux1);
    // 5) fused cumsum fold+add (X3 in place) + scan chunk pass
    k_cs23_scan1<<<(2 * NCH * DI) / BDIM, BDIM, 0, stream>>>(BXC, aux1, X3,
                                                             LD, auxA, auxS);
    // 6) scan final pass -> OUT (overlays dead XC)
    k_scan_p23<<<(2 * NCH * DI) / BDIM, BDIM, 0, stream>>>(LD, X3, auxA, auxS,
                                                           ZB, Dss, OUT);
    // 7) G7: out = OUT @ out_proj^T (f32)
    k_gemm<2><<<dim3(8, 64), BDIM, 0, stream>>>(OUT, WO, DI, nullptr, nullptr, 0,
                                                1024, out, nullptr);
}